// Round 13
// baseline (29.811 us; speedup 1.0000x reference)
//
#include <hip/hip_runtime.h>

// Problem constants: x[64][32768][15] f32, hidden sizes 4/4/4.
#define SEQ   64
#define BATCH 32768
#define FEAT  15
#define SLABBYTES (BATCH * FEAT * 4)   // 1,966,080 bytes per timestep slab

#define LOG2E 1.4426950408889634f

typedef float v2f __attribute__((ext_vector_type(2)));
typedef float v4f __attribute__((ext_vector_type(4)));

__device__ __forceinline__ float fast_rcp(float x) { return __builtin_amdgcn_rcpf(x); }
__device__ __forceinline__ float ex2(float x)      { return __builtin_amdgcn_exp2f(x); }
// sig2(t) = 1/(1+2^t).  sigmoid(x) = sig2(-L*x); tanh(x) = 1 - 2*sig2(2L*x).
__device__ __forceinline__ float sig2(float t)     { return fast_rcp(1.0f + ex2(t)); }

// Quad DPP: 0xB1=xor1, 0x4E=xor2, 0x1B=xor3 (quad_perm within each 4-lane group).
template <int CTRL>
__device__ __forceinline__ float qmov(float v) {
    return __int_as_float(
        __builtin_amdgcn_mov_dpp(__float_as_int(v), CTRL, 0xf, 0xf, false));
}
template <int CTRL>
__device__ __forceinline__ v2f qmov2(v2f v) {
    return v2f{qmov<CTRL>(v.x), qmov<CTRL>(v.y)};
}

// packed f32 fma -> v_pk_fma_f32
__device__ __forceinline__ v2f fma2(v2f a, v2f b, v2f c) { return a * b + c; }
__device__ __forceinline__ v2f sig2p(v2f t) { return v2f{sig2(t.x), sig2(t.y)}; }
__device__ __forceinline__ v2f sp(float v)  { return v2f{v, v}; }

template <int N>
__device__ __forceinline__ void waitv() {
    asm volatile("s_waitcnt vmcnt(%0)" :: "n"(N) : "memory");
}

typedef const __attribute__((address_space(1))) void gas_t;
typedef __attribute__((address_space(3))) void las_t;

__global__ __launch_bounds__(256, 1) void lstm_fused(
    const float* __restrict__ x,
    const float* __restrict__ w1,  const float* __restrict__ b1,
    const float* __restrict__ w2,  const float* __restrict__ b2,
    const float* __restrict__ wih, const float* __restrict__ whh,
    const float* __restrict__ bih, const float* __restrict__ bhh,
    const float* __restrict__ w3,  const float* __restrict__ b3,
    float* __restrict__ out)
{
    // 4 waves/block, 1 block/CU, 1 wave/SIMD. Each wave owns 32 elements:
    // quad q handles the PAIR (ebase+q, ebase+16+q), packed in v2f halves.
    // Per wave: 8 ring buffers x 2 KiB (32 rows x 64 B) = 16 KiB; 64 KiB/block.
    __shared__ __align__(16) float lds[4][8][512];

    const int tid = threadIdx.x;
    const int w   = tid >> 6;          // wave in block
    const int l   = tid & 63;          // lane
    const int u   = l & 3;             // lane-in-quad (owns hidden unit u)
    const int q   = l >> 2;            // quad index = row within 16-row group
    const int ebase = (blockIdx.x * 4 + w) * 32;
    const int elemA = ebase + q;
    const int elemB = ebase + 16 + q;

    // ---- DMA source pre-swizzle (dest linear: lane k -> bytes [16k,16k+16)) ----
    // Within each 16-row group: slot s of row r holds part p=(s-perm(r))&3,
    // perm(r)=(r+(r>>2))&3 (max 2-way bank alias). Parts: p0=bytes 0..15,
    // p1=16..31, p2=32..47, p3=44..59 (word-11 dup; never crosses slab end).
    const int perm_q = (q + (q >> 2)) & 3;
    const int p      = (u - perm_q) & 3;
    const int inrow  = (p < 3) ? p * 16 : 44;
    // gload 0 covers rows 0..15 (elems ebase..+15); gload 1 covers rows 16..31.
    uint32_t off = (uint32_t)(ebase + q) * 60u + (uint32_t)inrow;   // slab-0, group 0
    // group-1 source = off + 16 elems * 60 B = off + 960.

    auto gload2 = [&](int b) {
        __builtin_amdgcn_global_load_lds(
            (gas_t*)((const char*)x + off),
            (las_t*)&lds[w][b][0],   16, 0, 0);
        __builtin_amdgcn_global_load_lds(
            (gas_t*)((const char*)x + off + 960u),
            (las_t*)&lds[w][b][256], 16, 0, 0);
        off += SLABBYTES;
    };

    // reader-side slot bases (float index) for parts 0..3 of row q
    int sb[4];
#pragma unroll
    for (int pp = 0; pp < 4; ++pp) sb[pp] = (4 * q + ((pp + perm_q) & 3)) * 4;

    // ---- weights ----
    // fc1 (unit u), per-elem packed over features: chains A=(0,1)(4,5)(8,9)(0*,12),
    // B=(2,3)(6,7)(10,11)(13,14); word-11 dup in F3.x weight-zeroed.
    v2f PA0, PA1, PA2, PA3, PB0, PB1, PB2, PB3, SEEDv;
    {
        const float* r = w1 + u * FEAT;
        PA0 = v2f{r[0],  r[1]};  PB0 = v2f{r[2],  r[3]};
        PA1 = v2f{r[4],  r[5]};  PB1 = v2f{r[6],  r[7]};
        PA2 = v2f{r[8],  r[9]};  PB2 = v2f{r[10], r[11]};
        PA3 = v2f{0.0f,  r[12]}; PB3 = v2f{r[13], r[14]};
        SEEDv = v2f{b1[u], 0.0f};
    }
    // fc2 (unit u), xor-indexed, splat pairs (elem-packed), scaled -log2e
    v2f W2q[4], B2q;
#pragma unroll
    for (int k = 0; k < 4; ++k) W2q[k] = sp(-LOG2E * w2[u * 4 + (u ^ k)]);
    B2q = sp(-LOG2E * b2[u]);
    // gates (torch order i,f,g,o), xor-indexed splat pairs.
    v2f WIq[4][4], WHq[4][4], BIq[4];
#pragma unroll
    for (int g = 0; g < 4; ++g) {
        const float sg = (g == 2) ? (2.0f * LOG2E) : -LOG2E;
        const int row = (g * 4 + u) * 4;
#pragma unroll
        for (int k = 0; k < 4; ++k) {
            WIq[g][k] = sp(sg * wih[row + (u ^ k)]);
            WHq[g][k] = sp(sg * whh[row + (u ^ k)]);
        }
        BIq[g] = sp(sg * (bih[g * 4 + u] + bhh[g * 4 + u]));
    }
    const float W3v = -LOG2E * w3[u];
    const float B3v = -LOG2E * b3[0];

    v2f hp  = v2f{0.0f, 0.0f};   // hidden state, elem pair
    v2f csp = v2f{0.0f, 0.0f};   // scaled cell state: cs = 2*log2e*c

    auto step = [&](v4f FA0, v4f FA1, v4f FA2, v4f FA3,
                    v4f FB0, v4f FB1, v4f FB2, v4f FB3) {
        // fc1 per elem (feature-packed), then pair the scalars
        v2f aA = fma2(PA0, FA0.xy, fma2(PA1, FA1.xy,
                 fma2(PA2, FA2.xy, fma2(PA3, FA3.xy, SEEDv))));
        v2f bA = fma2(PB0, FA0.zw, fma2(PB1, FA1.zw,
                 fma2(PB2, FA2.zw, fma2(PB3, FA3.zw, v2f{0.0f, 0.0f}))));
        v2f aB = fma2(PA0, FB0.xy, fma2(PA1, FB1.xy,
                 fma2(PA2, FB2.xy, fma2(PA3, FB3.xy, SEEDv))));
        v2f bB = fma2(PB0, FB0.zw, fma2(PB1, FB1.zw,
                 fma2(PB2, FB2.zw, fma2(PB3, FB3.zw, v2f{0.0f, 0.0f}))));
        const v2f sA = aA + bA, sB = aB + bB;
        const v2f h1p = v2f{fmaxf(sA.x + sA.y, 0.0f), fmaxf(sB.x + sB.y, 0.0f)};
        // fc2 + sigmoid, elem-packed; xor-DPP neighbors
        const v2f H1 = qmov2<0xB1>(h1p), H2 = qmov2<0x4E>(h1p), H3 = qmov2<0x1B>(h1p);
        const v2f a2p = fma2(W2q[0], h1p, fma2(W2q[1], H1,
                        fma2(W2q[2], H2, fma2(W2q[3], H3, B2q))));
        const v2f h2p = sig2p(a2p);
        // gate dots, elem-packed (no hadds: k-sum is sequential pk_fma)
        const v2f Q1 = qmov2<0xB1>(h2p), Q2 = qmov2<0x4E>(h2p), Q3 = qmov2<0x1B>(h2p);
        const v2f P1 = qmov2<0xB1>(hp),  P2 = qmov2<0x4E>(hp),  P3 = qmov2<0x1B>(hp);
        v2f A[4];
#pragma unroll
        for (int g = 0; g < 4; ++g)
            A[g] = fma2(WIq[g][0], h2p, fma2(WIq[g][1], Q1,
                   fma2(WIq[g][2], Q2,  fma2(WIq[g][3], Q3,
                   fma2(WHq[g][0], hp,  fma2(WHq[g][1], P1,
                   fma2(WHq[g][2], P2,  fma2(WHq[g][3], P3, BIq[g]))))))));
        const v2f igp  = sig2p(A[0]);
        const v2f fgp  = sig2p(A[1]);
        const v2f gt2p = fma2(sp(-4.0f * LOG2E), sig2p(A[2]), sp(2.0f * LOG2E));
        const v2f ogp  = sig2p(A[3]);
        csp = fma2(fgp, csp, igp * gt2p);                 // cs = 2L*c
        const v2f tcp = fma2(sp(-2.0f), sig2p(csp), sp(1.0f));   // tanh(c)
        hp = ogp * tcp;
    };

#define LDROW(b, A0, A1, A2, A3, B0, B1, B2, B3)                     \
    {   const float* Bp = &lds[w][(b)][0];                           \
        A0 = *(const v4f*)(Bp + sb[0]);                              \
        A1 = *(const v4f*)(Bp + sb[1]);                              \
        A2 = *(const v4f*)(Bp + sb[2]);                              \
        A3 = *(const v4f*)(Bp + sb[3]);                              \
        B0 = *(const v4f*)(Bp + 256 + sb[0]);                        \
        B1 = *(const v4f*)(Bp + 256 + sb[1]);                        \
        B2 = *(const v4f*)(Bp + 256 + sb[2]);                        \
        B3 = *(const v4f*)(Bp + 256 + sb[3]);  }

    // ---- prologue: issue slabs 0..5 (12 DMAs); land slab 0; read rows(0) ----
#pragma unroll
    for (int b = 0; b < 6; ++b) gload2(b);
    waitv<10>();
    v4f FA0, FA1, FA2, FA3, FB0, FB1, FB2, FB3;
    LDROW(0, FA0, FA1, FA2, FA3, FB0, FB1, FB2, FB3);

    // ---- main: steps 0..55 (7 x 8, ring index = s&7) ----
    // Iter s: wait slab s+1 landed (outstanding -> 8 = slabs s+2..s+5);
    // read rows(s+1); issue slab s+6; compute step s.
#pragma unroll 1
    for (int ph = 0; ph < 7; ++ph) {
#pragma unroll
        for (int j = 0; j < 8; ++j) {
            waitv<8>();
            v4f NA0, NA1, NA2, NA3, NB0, NB1, NB2, NB3;
            LDROW((j + 1) & 7, NA0, NA1, NA2, NA3, NB0, NB1, NB2, NB3);
            gload2((j + 6) & 7);
            step(FA0, FA1, FA2, FA3, FB0, FB1, FB2, FB3);
            FA0 = NA0; FA1 = NA1; FA2 = NA2; FA3 = NA3;
            FB0 = NB0; FB1 = NB1; FB2 = NB2; FB3 = NB3;
        }
    }
    // ---- steps 56,57: issue last slabs 62,63 ----
#define TAIL(BN, GB, NN)                                              \
    {   waitv<NN>();                                                  \
        v4f NA0, NA1, NA2, NA3, NB0, NB1, NB2, NB3;                   \
        LDROW((BN), NA0, NA1, NA2, NA3, NB0, NB1, NB2, NB3);          \
        if ((GB) >= 0) gload2(GB);                                    \
        step(FA0, FA1, FA2, FA3, FB0, FB1, FB2, FB3);                 \
        FA0 = NA0; FA1 = NA1; FA2 = NA2; FA3 = NA3;                   \
        FB0 = NB0; FB1 = NB1; FB2 = NB2; FB3 = NB3;  }
    TAIL(1, 6, 8)   // s=56: read slab 57, issue slab 62
    TAIL(2, 7, 8)   // s=57: read slab 58, issue slab 63
    TAIL(3, -1, 8)  // s=58: read slab 59
    TAIL(4, -1, 6)  // s=59: read slab 60
    TAIL(5, -1, 4)  // s=60: read slab 61
    TAIL(6, -1, 2)  // s=61: read slab 62
    TAIL(7, -1, 0)  // s=62: read slab 63
#undef TAIL
    step(FA0, FA1, FA2, FA3, FB0, FB1, FB2, FB3);   // step 63
#undef LDROW

    // ---- head: out = sigmoid(w3·h + b3), quad reduction, both elems ----
    v2f prp = sp(W3v) * hp;
    prp += qmov2<0xB1>(prp);
    prp += qmov2<0x4E>(prp);
    if (u == 0) {
        out[elemA] = sig2(prp.x + B3v);
        out[elemB] = sig2(prp.y + B3v);
    }
}

extern "C" void kernel_launch(void* const* d_in, const int* in_sizes, int n_in,
                              void* d_out, int out_size, void* d_ws, size_t ws_size,
                              hipStream_t stream) {
    (void)in_sizes; (void)n_in; (void)d_ws; (void)ws_size; (void)out_size;
    const float* x   = (const float*)d_in[0];
    const float* w1  = (const float*)d_in[1];
    const float* b1  = (const float*)d_in[2];
    const float* w2  = (const float*)d_in[3];
    const float* b2  = (const float*)d_in[4];
    const float* wih = (const float*)d_in[5];
    const float* whh = (const float*)d_in[6];
    const float* bih = (const float*)d_in[7];
    const float* bhh = (const float*)d_in[8];
    const float* w3  = (const float*)d_in[9];
    const float* b3  = (const float*)d_in[10];
    float* out = (float*)d_out;

    // 256 blocks x 256 threads = 1024 waves; each wave owns 32 elements
    // (16 quads x elem-pair packed in v2f halves).
    lstm_fused<<<dim3(256), dim3(256), 0, stream>>>(
        x, w1, b1, w2, b2, wih, whh, bih, bhh, w3, b3, out);
}

// Round 14
// 29.401 us; speedup vs baseline: 1.0139x; 1.0139x over previous
//
#include <hip/hip_runtime.h>

// Problem constants: x[64][32768][15] f32, hidden sizes 4/4/4.
#define SEQ   64
#define BATCH 32768
#define FEAT  15
#define SLABBYTES (BATCH * FEAT * 4)   // 1,966,080 bytes per timestep slab

#define LOG2E 1.4426950408889634f

typedef float v2f __attribute__((ext_vector_type(2)));
typedef float v4f __attribute__((ext_vector_type(4)));

__device__ __forceinline__ float fast_rcp(float x) { return __builtin_amdgcn_rcpf(x); }
__device__ __forceinline__ float ex2(float x)      { return __builtin_amdgcn_exp2f(x); }
// sig2(t) = 1/(1+2^t).  sigmoid(x) = sig2(-L*x); tanh(x) = 1 - 2*sig2(2L*x).
__device__ __forceinline__ float sig2(float t)     { return fast_rcp(1.0f + ex2(t)); }

// Quad DPP: 0xB1=xor1, 0x4E=xor2, 0x1B=xor3 (quad_perm within each 4-lane group).
template <int CTRL>
__device__ __forceinline__ float qmov(float v) {
    return __int_as_float(
        __builtin_amdgcn_mov_dpp(__float_as_int(v), CTRL, 0xf, 0xf, false));
}

// packed f32 fma -> v_pk_fma_f32
__device__ __forceinline__ v2f fma2(v2f a, v2f b, v2f c) { return a * b + c; }

template <int N>
__device__ __forceinline__ void waitv() {
    asm volatile("s_waitcnt vmcnt(%0)" :: "n"(N) : "memory");
}

typedef const __attribute__((address_space(1))) void gas_t;
typedef __attribute__((address_space(3))) void las_t;

__global__ __launch_bounds__(256, 2) void lstm_fused(
    const float* __restrict__ x,
    const float* __restrict__ w1,  const float* __restrict__ b1,
    const float* __restrict__ w2,  const float* __restrict__ b2,
    const float* __restrict__ wih, const float* __restrict__ whh,
    const float* __restrict__ bih, const float* __restrict__ bhh,
    const float* __restrict__ w3,  const float* __restrict__ b3,
    float* __restrict__ out)
{
    // 4 waves/block; per wave: 8 LDS buffers (1 KiB each), 4-6 DMAs outstanding,
    // double-step pacing. Steps execute BEFORE the vmcnt wait so VALU work
    // overlaps the DMA completion interval instead of following it.
    __shared__ __align__(16) float lds[4][8][256];

    const int tid = threadIdx.x;
    const int w   = tid >> 6;          // wave in block
    const int l   = tid & 63;          // lane
    const int u   = l & 3;             // lane-in-quad (owns hidden unit u)
    const int e   = l >> 2;            // element (=row) within the wave's 16
    const int ebase = blockIdx.x * 64 + w * 16;
    const int elem  = ebase + e;

    // ---- DMA source pre-swizzle (dest linear: lane k -> bytes [16k,16k+16)) ----
    // slot q of row r holds part p=(q-perm(r))&3, perm(r)=(r+(r>>2))&3 (2-way max).
    // Parts: p0=bytes 0..15, p1=16..31, p2=32..47, p3=44..59 (word-11 dup, no OOB).
    const int perm_e = (e + (e >> 2)) & 3;
    const int p      = (u - perm_e) & 3;
    const int inrow  = (p < 3) ? p * 16 : 44;
    uint32_t off = (uint32_t)(ebase + e) * 60u + (uint32_t)inrow;   // slab-0 source byte

    auto gload = [&](int b) {
        __builtin_amdgcn_global_load_lds(
            (gas_t*)((const char*)x + off),
            (las_t*)&lds[w][b][0], 16, 0, 0);
        off += SLABBYTES;
    };

    int sb[4];
#pragma unroll
    for (int pp = 0; pp < 4; ++pp) sb[pp] = (4 * e + ((pp + perm_e) & 3)) * 4;

    auto ldrow = [&](int b, v4f& F0, v4f& F1, v4f& F2, v4f& F3) {
        const float* B = &lds[w][b][0];
        F0 = *(const v4f*)(B + sb[0]);   // words 0..3
        F1 = *(const v4f*)(B + sb[1]);   // words 4..7
        F2 = *(const v4f*)(B + sb[2]);   // words 8..11
        F3 = *(const v4f*)(B + sb[3]);   // words 11..14 (x = dup of 11)
    };

    // ---- weights ----
    // fc1 (unit u): chains A=(0,1)(4,5)(8,9)(0*,12), B=(2,3)(6,7)(10,11)(13,14).
    v2f PA0, PA1, PA2, PA3, PB0, PB1, PB2, PB3, SEEDv;
    {
        const float* r = w1 + u * FEAT;
        PA0 = v2f{r[0],  r[1]};  PB0 = v2f{r[2],  r[3]};
        PA1 = v2f{r[4],  r[5]};  PB1 = v2f{r[6],  r[7]};
        PA2 = v2f{r[8],  r[9]};  PB2 = v2f{r[10], r[11]};
        PA3 = v2f{0.0f,  r[12]}; PB3 = v2f{r[13], r[14]};
        SEEDv = v2f{b1[u], 0.0f};
    }
    // fc2 (unit u), xor-permuted: a2n = sum_k w2[u][u^k] * h1[u^k], scaled -log2e
    const v2f W2X01 = v2f{-LOG2E * w2[u * 4 + u],       -LOG2E * w2[u * 4 + (u ^ 1)]};
    const v2f W2X23 = v2f{-LOG2E * w2[u * 4 + (u ^ 2)], -LOG2E * w2[u * 4 + (u ^ 3)]};
    const v2f B2seed = v2f{-LOG2E * b2[u], 0.0f};
    // gates (torch order i,f,g,o), xor-permuted over the source index.
    v2f WIx[4][2], WHx[4][2], BIg[4];
#pragma unroll
    for (int g = 0; g < 4; ++g) {
        const float sg = (g == 2) ? (2.0f * LOG2E) : -LOG2E;
        const int row = (g * 4 + u) * 4;
        WIx[g][0] = v2f{sg * wih[row + u],       sg * wih[row + (u ^ 1)]};
        WIx[g][1] = v2f{sg * wih[row + (u ^ 2)], sg * wih[row + (u ^ 3)]};
        WHx[g][0] = v2f{sg * whh[row + u],       sg * whh[row + (u ^ 1)]};
        WHx[g][1] = v2f{sg * whh[row + (u ^ 2)], sg * whh[row + (u ^ 3)]};
        BIg[g]    = v2f{sg * (bih[g * 4 + u] + bhh[g * 4 + u]), 0.0f};
    }
    const float W3v = -LOG2E * w3[u];
    const float B3v = -LOG2E * b3[0];

    float h = 0.0f;
    float cs = 0.0f;   // scaled cell state: cs = 2*log2e * c

    auto step = [&](v4f F0, v4f F1, v4f F2, v4f F3) {
        // fc1 (unit u): 8 pk_fma over aligned v2f slices
        v2f accA = fma2(PA0, F0.xy, fma2(PA1, F1.xy,
                   fma2(PA2, F2.xy, fma2(PA3, F3.xy, SEEDv))));
        v2f accB = fma2(PB0, F0.zw, fma2(PB1, F1.zw,
                   fma2(PB2, F2.zw, fma2(PB3, F3.zw, v2f{0.0f, 0.0f}))));
        const v2f accS = accA + accB;
        const float h1 = fmaxf(accS.x + accS.y, 0.0f);
        // fc2 + sigmoid via xor-DPP fetch (own + 3 neighbors)
        const v2f H01 = v2f{h1, qmov<0xB1>(h1)};
        const v2f H23 = v2f{qmov<0x4E>(h1), qmov<0x1B>(h1)};
        const v2f a2 = fma2(W2X01, H01, fma2(W2X23, H23, B2seed));
        const float h2 = sig2(a2.x + a2.y);
        // gate dots: xor-DPP pairs for h2 and h
        const v2f Q01 = v2f{h2, qmov<0xB1>(h2)};
        const v2f Q23 = v2f{qmov<0x4E>(h2), qmov<0x1B>(h2)};
        const v2f P01 = v2f{h, qmov<0xB1>(h)};
        const v2f P23 = v2f{qmov<0x4E>(h), qmov<0x1B>(h)};
        v2f A[4];
#pragma unroll
        for (int g = 0; g < 4; ++g)
            A[g] = fma2(WIx[g][0], Q01, fma2(WIx[g][1], Q23,
                   fma2(WHx[g][0], P01, fma2(WHx[g][1], P23, BIg[g]))));
        const float ig = sig2(A[0].x + A[0].y);
        const float fg = sig2(A[1].x + A[1].y);
        const float gt2 = fmaf(-4.0f * LOG2E, sig2(A[2].x + A[2].y), 2.0f * LOG2E);
        const float og = sig2(A[3].x + A[3].y);
        cs = fmaf(fg, cs, ig * gt2);               // cs = 2L*c
        const float tc = fmaf(-2.0f, sig2(cs), 1.0f);   // tanh(c)
        h = og * tc;
    };

    // ---- prologue: issue slabs 0..5; land 0,1; read rows 0,1 ----
#pragma unroll
    for (int b = 0; b < 6; ++b) gload(b);
    waitv<4>();
    v4f F0, F1, F2, F3, G0, G1, G2, G3;
    ldrow(0, F0, F1, F2, F3);
    ldrow(1, G0, G1, G2, G3);

    // ---- main: double-steps D=0..27 (7 phases x 4) ----
    // Iter D: compute steps 2D,2D+1 FIRST (overlaps outstanding DMAs);
    // then wait slabs 2D+2,2D+3 landed; read rows 2D+2,2D+3;
    // issue slabs 2D+6,2D+7 into buffers freed at iter D-2.
#pragma unroll 1
    for (int ph = 0; ph < 7; ++ph) {
#pragma unroll
        for (int d = 0; d < 4; ++d) {              // D = 4*ph + d
            step(F0, F1, F2, F3);                  // step 2D
            step(G0, G1, G2, G3);                  // step 2D+1
            waitv<2>();
            ldrow((2 * d + 2) & 7, F0, F1, F2, F3);
            ldrow((2 * d + 3) & 7, G0, G1, G2, G3);
            gload((2 * d + 6) & 7);
            gload((2 * d + 7) & 7);
            __builtin_amdgcn_sched_barrier(0);
        }
    }
    {   // D=28: steps 56,57; land 58,59; read rows 58,59; issue slabs 62,63
        step(F0, F1, F2, F3);
        step(G0, G1, G2, G3);
        waitv<2>();
        ldrow(2, F0, F1, F2, F3);
        ldrow(3, G0, G1, G2, G3);
        gload(6);
        gload(7);
        __builtin_amdgcn_sched_barrier(0);
    }
    {   // D=29: steps 58,59; land 60,61; read rows 60,61
        step(F0, F1, F2, F3);
        step(G0, G1, G2, G3);
        waitv<2>();
        ldrow(4, F0, F1, F2, F3);
        ldrow(5, G0, G1, G2, G3);
        __builtin_amdgcn_sched_barrier(0);
    }
    {   // D=30: steps 60,61; land 62,63; read rows 62,63
        step(F0, F1, F2, F3);
        step(G0, G1, G2, G3);
        waitv<0>();
        ldrow(6, F0, F1, F2, F3);
        ldrow(7, G0, G1, G2, G3);
        __builtin_amdgcn_sched_barrier(0);
    }
    step(F0, F1, F2, F3);                          // step 62
    step(G0, G1, G2, G3);                          // step 63

    // ---- head: out[e] = sigmoid(w3·h + b3), quad reduction (scaled) ----
    float pr = W3v * h;
    pr += qmov<0xB1>(pr);
    pr += qmov<0x4E>(pr);
    if (u == 0) out[elem] = sig2(pr + B3v);
}

extern "C" void kernel_launch(void* const* d_in, const int* in_sizes, int n_in,
                              void* d_out, int out_size, void* d_ws, size_t ws_size,
                              hipStream_t stream) {
    (void)in_sizes; (void)n_in; (void)d_ws; (void)ws_size; (void)out_size;
    const float* x   = (const float*)d_in[0];
    const float* w1  = (const float*)d_in[1];
    const float* b1  = (const float*)d_in[2];
    const float* w2  = (const float*)d_in[3];
    const float* b2  = (const float*)d_in[4];
    const float* wih = (const float*)d_in[5];
    const float* whh = (const float*)d_in[6];
    const float* bih = (const float*)d_in[7];
    const float* bhh = (const float*)d_in[8];
    const float* w3  = (const float*)d_in[9];
    const float* b3  = (const float*)d_in[10];
    float* out = (float*)d_out;

    // 512 blocks x 256 threads = 2048 waves; one quad (4 lanes) per batch element.
    lstm_fused<<<dim3(512), dim3(256), 0, stream>>>(
        x, w1, b1, w2, b2, wih, whh, bih, bhh, w3, b3, out);
}